// Round 4
// baseline (260.624 us; speedup 1.0000x reference)
//
#include <hip/hip_runtime.h>
#include <hip/hip_bf16.h>
#include <math.h>

// COLoRALinear: B=4, S=2048, D_IN=D_OUT=2048, E=8, R=8, SCALING=2.0
#define BATCH 4
#define SEQ   2048
#define DIN   2048
#define DOUT  2048
#define NEXP  8
#define RANK  8
#define MTOT  (BATCH * SEQ)   // 8192
#define KP    128             // padded low-rank K: 64 expert + 8 shared + 56 zero

typedef __bf16 bf16x8 __attribute__((ext_vector_type(8)));
typedef __bf16 bf16x4 __attribute__((ext_vector_type(4)));
typedef float  f32x4  __attribute__((ext_vector_type(4)));

#define GLOBAL_AS __attribute__((address_space(1)))
#define LDS_AS    __attribute__((address_space(3)))

// ---------------------------------------------------------------------------
// K1: fused prep (6400 blocks):
//  [0,256):     x -> xb (bf16) + per-64-row column partial sums -> partial[b][sc][i]
//  [256,4352):  W -> Wb (bf16)
//  [4352,5376): caug[o][k]: k<64 -> (1-cw)*2*expert_B[e][o][r];
//               64..71 -> cw*2*shared_B[o][k-64]; else 0  (routing applied in K2)
//  [5376,6400): Ab[k][i]: k<64 -> expert_A[k][i]; 64..71 -> shared_A; else 0
// ---------------------------------------------------------------------------
__global__ __launch_bounds__(256) void prep_all(
    const float* __restrict__ x, const float* __restrict__ W,
    const float* __restrict__ expert_A, const float* __restrict__ shared_A,
    const float* __restrict__ expert_B, const float* __restrict__ shared_B,
    const float* __restrict__ collab,
    __bf16* __restrict__ xb, float* __restrict__ partial,
    __bf16* __restrict__ Wb, __bf16* __restrict__ caug, __bf16* __restrict__ Ab)
{
    const int bid = blockIdx.x;
    const int t = threadIdx.x;
    if (bid < 256) {
        const int dc = bid & 1, sc = (bid >> 1) & 31, b = bid >> 6;
        const int i = dc * 1024 + t * 4;
        size_t base = ((size_t)b * SEQ + (size_t)sc * 64) * DIN + i;
        float ax = 0.f, ay = 0.f, az = 0.f, aw = 0.f;
        for (int s = 0; s < 64; ++s) {
            float4 v = *(const float4*)&x[base + (size_t)s * DIN];
            ax += v.x; ay += v.y; az += v.z; aw += v.w;
            bf16x4 h = { (__bf16)v.x, (__bf16)v.y, (__bf16)v.z, (__bf16)v.w };
            *(bf16x4*)&xb[base + (size_t)s * DIN] = h;
        }
        float4 p = { ax, ay, az, aw };
        *(float4*)&partial[((size_t)b * 32 + sc) * DIN + i] = p;
    } else if (bid < 4352) {
        size_t idx = ((size_t)(bid - 256) * 256 + t) * 4;
        float4 v = *(const float4*)&W[idx];
        bf16x4 h = { (__bf16)v.x, (__bf16)v.y, (__bf16)v.z, (__bf16)v.w };
        *(bf16x4*)&Wb[idx] = h;
    } else if (bid < 5376) {
        int idx = (bid - 4352) * 256 + t;      // 2048*128
        int k = idx & 127, o = idx >> 7;
        float cw = 1.0f / (1.0f + expf(-collab[0]));
        float v = 0.f;
        if (k < 64)
            v = (1.0f - cw) * 2.0f * expert_B[((size_t)(k >> 3) * DOUT + o) * RANK + (k & 7)];
        else if (k < 72)
            v = cw * 2.0f * shared_B[(size_t)o * RANK + (k - 64)];
        caug[idx] = (__bf16)v;
    } else {
        int idx = (bid - 5376) * 256 + t;      // 128*2048: [k][i]
        int i = idx & 2047, k = idx >> 11;
        float v = 0.f;
        if (k < 64)      v = expert_A[(size_t)k * DIN + i];
        else if (k < 72) v = shared_A[(size_t)(k - 64) * DIN + i];
        Ab[idx] = (__bf16)v;
    }
}

// ---------------------------------------------------------------------------
// K2 (64 blocks): per 128-row m-tile:
//  (1) redundantly compute routing softmax for batch b = m0>>11 from partials
//  (2) t = xb[m-tile] @ Ab^T over full K=2048 (m97 BK=32 structure)
//  (3) tb[m][k] = bf16( t * (k<64 ? routing[b][k>>3] : 1) )
// ---------------------------------------------------------------------------
__global__ __launch_bounds__(256) void gemm_t64(
    const __bf16* __restrict__ xb, const __bf16* __restrict__ Ab,
    const float* __restrict__ partial, const float* __restrict__ task_emb,
    __bf16* __restrict__ tb)
{
    __shared__ __bf16 lsA[128 * 32];
    __shared__ __bf16 lsB[128 * 32];
    __shared__ float red[256];
    __shared__ float rs[NEXP];
    const int t = threadIdx.x;
    const int m0 = blockIdx.x * 128;
    const int b  = m0 >> 11;

    // --- (1) routing ---
    float xm[8] = {0.f,0.f,0.f,0.f,0.f,0.f,0.f,0.f};
    for (int sc = 0; sc < 32; ++sc) {
        const float* pp = partial + ((size_t)b * 32 + sc) * DIN + t * 8;
        float4 v0 = *(const float4*)pp, v1 = *(const float4*)(pp + 4);
        xm[0] += v0.x; xm[1] += v0.y; xm[2] += v0.z; xm[3] += v0.w;
        xm[4] += v1.x; xm[5] += v1.y; xm[6] += v1.z; xm[7] += v1.w;
    }
    float le[NEXP];
    #pragma unroll
    for (int e = 0; e < NEXP; ++e) {
        const float* te = task_emb + (size_t)e * DIN + t * 8;
        float4 u0 = *(const float4*)te, u1 = *(const float4*)(te + 4);
        le[e] = xm[0]*u0.x + xm[1]*u0.y + xm[2]*u0.z + xm[3]*u0.w
              + xm[4]*u1.x + xm[5]*u1.y + xm[6]*u1.z + xm[7]*u1.w;
    }
    for (int e = 0; e < NEXP; ++e) {
        red[t] = le[e];
        __syncthreads();
        for (int s = 128; s > 0; s >>= 1) {
            if (t < s) red[t] += red[t + s];
            __syncthreads();
        }
        if (t == 0) rs[e] = red[0] * (1.0f / (float)SEQ);
        __syncthreads();
    }
    if (t == 0) {
        float mx = rs[0];
        for (int e = 1; e < NEXP; ++e) mx = fmaxf(mx, rs[e]);
        float ex[NEXP], den = 0.f;
        for (int e = 0; e < NEXP; ++e) { ex[e] = expf(rs[e] - mx); den += ex[e]; }
        for (int e = 0; e < NEXP; ++e) rs[e] = ex[e] / den;
    }
    // (visible to all threads after the first __syncthreads of the GEMM loop)

    // --- (2) GEMM ---
    const int lane = t & 63;
    const int wm = (t >> 6) >> 1, wn = (t >> 6) & 1;
    f32x4 acc[4][4];
    #pragma unroll
    for (int a = 0; a < 4; ++a)
        #pragma unroll
        for (int c = 0; c < 4; ++c) acc[a][c] = (f32x4){0.f, 0.f, 0.f, 0.f};

    for (int k0 = 0; k0 < DIN; k0 += 32) {
        #pragma unroll
        for (int q = 0; q < 2; ++q) {
            int L = q * 256 + t;
            int row = L >> 2, seg = L & 3;
            const __bf16* gpA = xb + (size_t)(m0 + row) * DIN + k0 + seg * 8;
            const __bf16* gpB = Ab + (size_t)row * DIN + k0 + seg * 8;
            int Lu = q * 256 + (t & ~63);
            __builtin_amdgcn_global_load_lds((GLOBAL_AS void*)gpA,
                (LDS_AS void*)&lsA[Lu * 8], 16, 0, 0);
            __builtin_amdgcn_global_load_lds((GLOBAL_AS void*)gpB,
                (LDS_AS void*)&lsB[Lu * 8], 16, 0, 0);
        }
        __syncthreads();
        bf16x8 af[4], bfr[4];
        #pragma unroll
        for (int tm = 0; tm < 4; ++tm)
            af[tm]  = *(const bf16x8*)&lsA[(wm * 64 + tm * 16 + (lane & 15)) * 32 + (lane >> 4) * 8];
        #pragma unroll
        for (int tn = 0; tn < 4; ++tn)
            bfr[tn] = *(const bf16x8*)&lsB[(wn * 64 + tn * 16 + (lane & 15)) * 32 + (lane >> 4) * 8];
        #pragma unroll
        for (int tm = 0; tm < 4; ++tm)
            #pragma unroll
            for (int tn = 0; tn < 4; ++tn)
                acc[tm][tn] = __builtin_amdgcn_mfma_f32_16x16x32_bf16(
                    af[tm], bfr[tn], acc[tm][tn], 0, 0, 0);
        __syncthreads();
    }

    // --- (3) scaled epilogue ---
    #pragma unroll
    for (int tm = 0; tm < 4; ++tm)
        #pragma unroll
        for (int tn = 0; tn < 4; ++tn) {
            int col = wn * 64 + tn * 16 + (lane & 15);
            float f = (col < 64) ? rs[col >> 3] : 1.0f;
            #pragma unroll
            for (int v = 0; v < 4; ++v) {
                int row = m0 + wm * 64 + tm * 16 + (lane >> 4) * 4 + v;
                tb[(size_t)row * KP + col] = (__bf16)(acc[tm][tn][v] * f);
            }
        }
}

// ---------------------------------------------------------------------------
// K3: out = xb @ Wb^T + tb @ caug^T + bias
// BK=64, 8-slot XOR swizzle, hoisted addressing (pointer-increment staging,
// K-invariant fragment offsets). grid (x=64 m-tiles, y=16 n-tiles) for XCD
// locality on the shared A-tile.
// ---------------------------------------------------------------------------
__global__ __launch_bounds__(256) void gemm_main(
    const __bf16* __restrict__ xb, const __bf16* __restrict__ Wb,
    const __bf16* __restrict__ tb, const __bf16* __restrict__ caug,
    const float* __restrict__ bias, float* __restrict__ out)
{
    __shared__ __bf16 lsA[128 * 64];
    __shared__ __bf16 lsB[128 * 64];
    const int t = threadIdx.x;
    const int lane = t & 63;
    const int wm = (t >> 6) >> 1, wn = (t >> 6) & 1;
    const int m0 = blockIdx.x * 128;
    const int n0 = blockIdx.y * 128;

    // per-thread staging constants (K-invariant)
    int rowq[4], segq[4], ldso[4];
    #pragma unroll
    for (int q = 0; q < 4; ++q) {
        rowq[q] = q * 32 + (t >> 3);
        segq[q] = (t & 7) ^ (rowq[q] & 7);
        ldso[q] = (q * 256 + (t & ~63)) * 8;
    }
    const __bf16* pA[4]; const __bf16* pB[4];
    #pragma unroll
    for (int q = 0; q < 4; ++q) {
        pA[q] = xb + (size_t)(m0 + rowq[q]) * DIN + segq[q] * 8;
        pB[q] = Wb + (size_t)(n0 + rowq[q]) * DIN + segq[q] * 8;
    }
    // K-invariant fragment LDS offsets
    int aoff[2][4], boff[2][4];
    #pragma unroll
    for (int tm = 0; tm < 4; ++tm) {
        int r = wm * 64 + tm * 16 + (lane & 15);
        #pragma unroll
        for (int kk = 0; kk < 2; ++kk)
            aoff[kk][tm] = r * 64 + (((kk * 4 + (lane >> 4)) ^ (r & 7)) * 8);
    }
    #pragma unroll
    for (int tn = 0; tn < 4; ++tn) {
        int r = wn * 64 + tn * 16 + (lane & 15);
        #pragma unroll
        for (int kk = 0; kk < 2; ++kk)
            boff[kk][tn] = r * 64 + (((kk * 4 + (lane >> 4)) ^ (r & 7)) * 8);
    }

    f32x4 acc[4][4];
    #pragma unroll
    for (int a = 0; a < 4; ++a)
        #pragma unroll
        for (int c = 0; c < 4; ++c) acc[a][c] = (f32x4){0.f, 0.f, 0.f, 0.f};

    // main: K = 2048 over (xb, Wb), 32 iters of BK=64
    for (int it = 0; it < 32; ++it) {
        #pragma unroll
        for (int q = 0; q < 4; ++q) {
            __builtin_amdgcn_global_load_lds((GLOBAL_AS void*)pA[q],
                (LDS_AS void*)&lsA[ldso[q]], 16, 0, 0);
            __builtin_amdgcn_global_load_lds((GLOBAL_AS void*)pB[q],
                (LDS_AS void*)&lsB[ldso[q]], 16, 0, 0);
            pA[q] += 64; pB[q] += 64;
        }
        __syncthreads();
        #pragma unroll
        for (int kk = 0; kk < 2; ++kk) {
            bf16x8 af[4], bfr[4];
            #pragma unroll
            for (int tm = 0; tm < 4; ++tm) af[tm]  = *(const bf16x8*)&lsA[aoff[kk][tm]];
            #pragma unroll
            for (int tn = 0; tn < 4; ++tn) bfr[tn] = *(const bf16x8*)&lsB[boff[kk][tn]];
            #pragma unroll
            for (int tm = 0; tm < 4; ++tm)
                #pragma unroll
                for (int tn = 0; tn < 4; ++tn)
                    acc[tm][tn] = __builtin_amdgcn_mfma_f32_16x16x32_bf16(
                        af[tm], bfr[tn], acc[tm][tn], 0, 0, 0);
        }
        __syncthreads();
    }

    // correction: K = 128 (zeros beyond 72) over (tb, caug), 2 iters
    const __bf16* qA[4]; const __bf16* qB[4];
    #pragma unroll
    for (int q = 0; q < 4; ++q) {
        qA[q] = tb   + (size_t)(m0 + rowq[q]) * KP + segq[q] * 8;
        qB[q] = caug + (size_t)(n0 + rowq[q]) * KP + segq[q] * 8;
    }
    for (int it = 0; it < 2; ++it) {
        #pragma unroll
        for (int q = 0; q < 4; ++q) {
            __builtin_amdgcn_global_load_lds((GLOBAL_AS void*)qA[q],
                (LDS_AS void*)&lsA[ldso[q]], 16, 0, 0);
            __builtin_amdgcn_global_load_lds((GLOBAL_AS void*)qB[q],
                (LDS_AS void*)&lsB[ldso[q]], 16, 0, 0);
            qA[q] += 64; qB[q] += 64;
        }
        __syncthreads();
        #pragma unroll
        for (int kk = 0; kk < 2; ++kk) {
            bf16x8 af[4], bfr[4];
            #pragma unroll
            for (int tm = 0; tm < 4; ++tm) af[tm]  = *(const bf16x8*)&lsA[aoff[kk][tm]];
            #pragma unroll
            for (int tn = 0; tn < 4; ++tn) bfr[tn] = *(const bf16x8*)&lsB[boff[kk][tn]];
            #pragma unroll
            for (int tm = 0; tm < 4; ++tm)
                #pragma unroll
                for (int tn = 0; tn < 4; ++tn)
                    acc[tm][tn] = __builtin_amdgcn_mfma_f32_16x16x32_bf16(
                        af[tm], bfr[tn], acc[tm][tn], 0, 0, 0);
        }
        __syncthreads();
    }

    #pragma unroll
    for (int tm = 0; tm < 4; ++tm)
        #pragma unroll
        for (int tn = 0; tn < 4; ++tn) {
            int col = n0 + wn * 64 + tn * 16 + (lane & 15);
            float bv = bias[col];
            #pragma unroll
            for (int v = 0; v < 4; ++v) {
                int row = m0 + wm * 64 + tm * 16 + (lane >> 4) * 4 + v;
                out[(size_t)row * DOUT + col] = acc[tm][tn][v] + bv;
            }
        }
}

// ---------------------------------------------------------------------------
// Workspace (bytes):
//   xb      @ 0         : 33,554,432   (8192x2048 bf16)
//   Wb      @ 33554432  :  8,388,608   (2048x2048 bf16)
//   tb      @ 41943040  :  2,097,152   (8192x128 bf16)
//   caug    @ 44040192  :    524,288   (2048x128 bf16)
//   Ab      @ 44564480  :    524,288   (128x2048 bf16)
//   partial @ 45088768  :  1,048,576   (4x32x2048 f32)
// ---------------------------------------------------------------------------
extern "C" void kernel_launch(void* const* d_in, const int* in_sizes, int n_in,
                              void* d_out, int out_size, void* d_ws, size_t ws_size,
                              hipStream_t stream)
{
    const float* x        = (const float*)d_in[0];
    const float* base_W   = (const float*)d_in[1];
    const float* base_b   = (const float*)d_in[2];
    const float* shared_A = (const float*)d_in[3];
    const float* shared_B = (const float*)d_in[4];
    const float* expert_A = (const float*)d_in[5];
    const float* expert_B = (const float*)d_in[6];
    const float* task_emb = (const float*)d_in[7];
    const float* collab_w = (const float*)d_in[8];
    float* out = (float*)d_out;

    char* ws = (char*)d_ws;
    __bf16* xb      = (__bf16*)(ws + 0);
    __bf16* Wb      = (__bf16*)(ws + 33554432);
    __bf16* tb      = (__bf16*)(ws + 41943040);
    __bf16* caug    = (__bf16*)(ws + 44040192);
    __bf16* Ab      = (__bf16*)(ws + 44564480);
    float*  partial = (float*) (ws + 45088768);

    prep_all <<<dim3(6400), 256, 0, stream>>>(x, base_W, expert_A, shared_A,
                                              expert_B, shared_B, collab_w,
                                              xb, partial, Wb, caug, Ab);
    gemm_t64 <<<dim3(64), 256, 0, stream>>>(xb, Ab, partial, task_emb, tb);
    gemm_main<<<dim3(64, 16), 256, 0, stream>>>(xb, Wb, tb, caug, base_b, out);
}

// Round 5
// 242.428 us; speedup vs baseline: 1.0751x; 1.0751x over previous
//
#include <hip/hip_runtime.h>
#include <hip/hip_bf16.h>
#include <math.h>

// COLoRALinear: B=4, S=2048, D_IN=D_OUT=2048, E=8, R=8, SCALING=2.0
#define BATCH 4
#define SEQ   2048
#define DIN   2048
#define DOUT  2048
#define NEXP  8
#define RANK  8
#define MTOT  (BATCH * SEQ)   // 8192
#define KE    64              // expert-only aug rank (shared folded into Wb)

typedef __bf16 bf16x8 __attribute__((ext_vector_type(8)));
typedef __bf16 bf16x4 __attribute__((ext_vector_type(4)));
typedef float  f32x4  __attribute__((ext_vector_type(4)));

#define GLOBAL_AS __attribute__((address_space(1)))
#define LDS_AS    __attribute__((address_space(3)))

// ---------------------------------------------------------------------------
// K1: fused prep (5760 blocks):
//  [0,1024):    x -> xb (bf16) + 32-row column partial sums -> partial[b][64][2048]
//  [1024,5120): Wb = bf16(W + cw*2*shared_B@shared_A)   (shared LoRA folded in)
//  [5120,5632): caug[o][k]: (1-cw)*2*expert_B[k>>3][o][k&7]
//  [5632,5760): Ab = bf16(expert_A)  ([64][2048] contiguous)
// ---------------------------------------------------------------------------
__global__ __launch_bounds__(256) void prep_all(
    const float* __restrict__ x, const float* __restrict__ W,
    const float* __restrict__ expert_A, const float* __restrict__ shared_A,
    const float* __restrict__ expert_B, const float* __restrict__ shared_B,
    const float* __restrict__ collab,
    __bf16* __restrict__ xb, float* __restrict__ partial,
    __bf16* __restrict__ Wb, __bf16* __restrict__ caug, __bf16* __restrict__ Ab)
{
    const int bid = blockIdx.x;
    const int t = threadIdx.x;
    if (bid < 1024) {
        const int dc = bid & 3, sc = (bid >> 2) & 63, b = bid >> 8;
        const int i = dc * 512 + t * 2;
        size_t base = ((size_t)b * SEQ + (size_t)sc * 32) * DIN + i;
        float a0 = 0.f, a1 = 0.f;
        for (int s = 0; s < 32; ++s) {
            float2 v = *(const float2*)&x[base + (size_t)s * DIN];
            a0 += v.x; a1 += v.y;
            __bf16 h0 = (__bf16)v.x, h1 = (__bf16)v.y;
            ((__bf16*)&xb[base + (size_t)s * DIN])[0] = h0;
            ((__bf16*)&xb[base + (size_t)s * DIN])[1] = h1;
        }
        float2 p = { a0, a1 };
        *(float2*)&partial[((size_t)b * 64 + sc) * DIN + i] = p;
    } else if (bid < 5120) {
        int idx = (bid - 1024) * 1024 + t * 4;   // element index in [0, 2048*2048)
        int o = idx >> 11, i = idx & 2047;
        float cw = 1.0f / (1.0f + expf(-collab[0]));
        float s = cw * 2.0f;
        float4 w = *(const float4*)&W[idx];
        float dx = 0.f, dy = 0.f, dz = 0.f, dw = 0.f;
        #pragma unroll
        for (int r = 0; r < 8; ++r) {
            float bs = shared_B[(size_t)o * RANK + r];
            float4 as = *(const float4*)&shared_A[(size_t)r * DIN + i];
            dx += bs * as.x; dy += bs * as.y; dz += bs * as.z; dw += bs * as.w;
        }
        bf16x4 h = { (__bf16)(w.x + s * dx), (__bf16)(w.y + s * dy),
                     (__bf16)(w.z + s * dz), (__bf16)(w.w + s * dw) };
        *(bf16x4*)&Wb[idx] = h;
    } else if (bid < 5632) {
        int idx = (bid - 5120) * 256 + t;        // 2048*64
        int k = idx & 63, o = idx >> 6;
        float cw = 1.0f / (1.0f + expf(-collab[0]));
        caug[idx] = (__bf16)((1.0f - cw) * 2.0f *
            expert_B[((size_t)(k >> 3) * DOUT + o) * RANK + (k & 7)]);
    } else {
        int idx = (bid - 5632) * 1024 + t * 4;   // 64*2048 elements
        float4 v = *(const float4*)&expert_A[idx];
        bf16x4 h = { (__bf16)v.x, (__bf16)v.y, (__bf16)v.z, (__bf16)v.w };
        *(bf16x4*)&Ab[idx] = h;
    }
}

// ---------------------------------------------------------------------------
// K2 (260 blocks): bid<256: split-K-4 low-rank GEMM (block = 128 m-rows x 64 cols)
//   pt[kc][m][64] = bf16( xb[m][kc*512:+512] @ Ab[:, kc*512:+512]^T )
//   kc = bid&3, m-tile = bid>>2. 4 waves, each 32 rows x 64 cols (acc[2][4]).
// bid>=256: routing softmax for batch b = bid-256.
// ---------------------------------------------------------------------------
__global__ __launch_bounds__(256) void gemm_t_rout(
    const __bf16* __restrict__ xb, const __bf16* __restrict__ Ab,
    const float* __restrict__ partial, const float* __restrict__ task_emb,
    __bf16* __restrict__ pt, float* __restrict__ routing)
{
    __shared__ __bf16 lsA[128 * 32];
    __shared__ __bf16 lsB[64 * 32];
    __shared__ float red[256];
    const int bid = blockIdx.x;
    const int t = threadIdx.x;

    if (bid >= 256) {
        const int b = bid - 256;
        float xm[8] = {0.f,0.f,0.f,0.f,0.f,0.f,0.f,0.f};
        for (int sc = 0; sc < 64; ++sc) {
            const float* pp = partial + ((size_t)b * 64 + sc) * DIN + t * 8;
            float4 v0 = *(const float4*)pp, v1 = *(const float4*)(pp + 4);
            xm[0] += v0.x; xm[1] += v0.y; xm[2] += v0.z; xm[3] += v0.w;
            xm[4] += v1.x; xm[5] += v1.y; xm[6] += v1.z; xm[7] += v1.w;
        }
        float le[NEXP];
        #pragma unroll
        for (int e = 0; e < NEXP; ++e) {
            const float* te = task_emb + (size_t)e * DIN + t * 8;
            float4 u0 = *(const float4*)te, u1 = *(const float4*)(te + 4);
            le[e] = xm[0]*u0.x + xm[1]*u0.y + xm[2]*u0.z + xm[3]*u0.w
                  + xm[4]*u1.x + xm[5]*u1.y + xm[6]*u1.z + xm[7]*u1.w;
        }
        __shared__ float logits[NEXP];
        for (int e = 0; e < NEXP; ++e) {
            red[t] = le[e];
            __syncthreads();
            for (int s = 128; s > 0; s >>= 1) {
                if (t < s) red[t] += red[t + s];
                __syncthreads();
            }
            if (t == 0) logits[e] = red[0] * (1.0f / (float)SEQ);
            __syncthreads();
        }
        if (t == 0) {
            float mx = logits[0];
            for (int e = 1; e < NEXP; ++e) mx = fmaxf(mx, logits[e]);
            float ex[NEXP], den = 0.f;
            for (int e = 0; e < NEXP; ++e) { ex[e] = expf(logits[e] - mx); den += ex[e]; }
            for (int e = 0; e < NEXP; ++e) routing[b * NEXP + e] = ex[e] / den;
        }
        return;
    }

    const int lane = t & 63;
    const int w = t >> 6;                 // wave id: rows w*32 .. w*32+31
    const int kc = bid & 3;
    const int m0 = (bid >> 2) * 128;

    f32x4 acc[2][4];
    #pragma unroll
    for (int a = 0; a < 2; ++a)
        #pragma unroll
        for (int c = 0; c < 4; ++c) acc[a][c] = (f32x4){0.f, 0.f, 0.f, 0.f};

    for (int k0 = kc * 512; k0 < kc * 512 + 512; k0 += 32) {
        // stage A: 128 rows x 4 segs = 512 chunks, 2/thread
        #pragma unroll
        for (int q = 0; q < 2; ++q) {
            int L = q * 256 + t;
            int row = L >> 2, seg = L & 3;
            const __bf16* gpA = xb + (size_t)(m0 + row) * DIN + k0 + seg * 8;
            int Lu = q * 256 + (t & ~63);
            __builtin_amdgcn_global_load_lds((GLOBAL_AS void*)gpA,
                (LDS_AS void*)&lsA[Lu * 8], 16, 0, 0);
        }
        // stage B: 64 rows x 4 segs = 256 chunks, 1/thread
        {
            int row = t >> 2, seg = t & 3;
            const __bf16* gpB = Ab + (size_t)row * DIN + k0 + seg * 8;
            __builtin_amdgcn_global_load_lds((GLOBAL_AS void*)gpB,
                (LDS_AS void*)&lsB[(t & ~63) * 8], 16, 0, 0);
        }
        __syncthreads();
        bf16x8 af[2], bfr[4];
        #pragma unroll
        for (int tm = 0; tm < 2; ++tm)
            af[tm] = *(const bf16x8*)&lsA[(w * 32 + tm * 16 + (lane & 15)) * 32 + (lane >> 4) * 8];
        #pragma unroll
        for (int tn = 0; tn < 4; ++tn)
            bfr[tn] = *(const bf16x8*)&lsB[(tn * 16 + (lane & 15)) * 32 + (lane >> 4) * 8];
        #pragma unroll
        for (int tm = 0; tm < 2; ++tm)
            #pragma unroll
            for (int tn = 0; tn < 4; ++tn)
                acc[tm][tn] = __builtin_amdgcn_mfma_f32_16x16x32_bf16(
                    af[tm], bfr[tn], acc[tm][tn], 0, 0, 0);
        __syncthreads();
    }
    #pragma unroll
    for (int tm = 0; tm < 2; ++tm)
        #pragma unroll
        for (int tn = 0; tn < 4; ++tn) {
            int col = tn * 16 + (lane & 15);
            #pragma unroll
            for (int v = 0; v < 4; ++v) {
                int row = m0 + w * 32 + tm * 16 + (lane >> 4) * 4 + v;
                pt[((size_t)kc * MTOT + row) * KE + col] = (__bf16)acc[tm][tn][v];
            }
        }
}

// ---------------------------------------------------------------------------
// K3: tb[m][k] = bf16( routing[b(m)][k>>3] * sum_kc pt[kc][m][k] ), 512 blocks.
// ---------------------------------------------------------------------------
__global__ __launch_bounds__(256) void reduce_route(
    const __bf16* __restrict__ pt, const float* __restrict__ routing,
    __bf16* __restrict__ tb)
{
    size_t idx = ((size_t)blockIdx.x * 256 + threadIdx.x) * 4;  // over 8192*64
    int k0 = (int)(idx & 63);
    int m  = (int)(idx >> 6);
    int b  = m >> 11;
    float f = routing[b * NEXP + (k0 >> 3)];
    float sx = 0.f, sy = 0.f, sz = 0.f, sw = 0.f;
    #pragma unroll
    for (int kc = 0; kc < 4; ++kc) {
        bf16x4 v = *(const bf16x4*)&pt[(size_t)kc * MTOT * KE + idx];
        sx += (float)v[0]; sy += (float)v[1]; sz += (float)v[2]; sw += (float)v[3];
    }
    bf16x4 h = { (__bf16)(sx * f), (__bf16)(sy * f), (__bf16)(sz * f), (__bf16)(sw * f) };
    *(bf16x4*)&tb[idx] = h;
}

// ---------------------------------------------------------------------------
// K4: out = xb @ Wb^T + tb @ caug^T + bias
// BK=64, 8-slot XOR swizzle, hoisted addressing; correction is ONE kstep (KE=64).
// grid (x=64 m-tiles, y=16 n-tiles) for XCD locality on the shared A-tile.
// ---------------------------------------------------------------------------
__global__ __launch_bounds__(256) void gemm_main(
    const __bf16* __restrict__ xb, const __bf16* __restrict__ Wb,
    const __bf16* __restrict__ tb, const __bf16* __restrict__ caug,
    const float* __restrict__ bias, float* __restrict__ out)
{
    __shared__ __bf16 lsA[128 * 64];
    __shared__ __bf16 lsB[128 * 64];
    const int t = threadIdx.x;
    const int lane = t & 63;
    const int wm = (t >> 6) >> 1, wn = (t >> 6) & 1;
    const int m0 = blockIdx.x * 128;
    const int n0 = blockIdx.y * 128;

    int rowq[4], segq[4], ldso[4];
    #pragma unroll
    for (int q = 0; q < 4; ++q) {
        rowq[q] = q * 32 + (t >> 3);
        segq[q] = (t & 7) ^ (rowq[q] & 7);
        ldso[q] = (q * 256 + (t & ~63)) * 8;
    }
    const __bf16* pA[4]; const __bf16* pB[4];
    #pragma unroll
    for (int q = 0; q < 4; ++q) {
        pA[q] = xb + (size_t)(m0 + rowq[q]) * DIN + segq[q] * 8;
        pB[q] = Wb + (size_t)(n0 + rowq[q]) * DIN + segq[q] * 8;
    }
    int aoff[2][4], boff[2][4];
    #pragma unroll
    for (int tm = 0; tm < 4; ++tm) {
        int r = wm * 64 + tm * 16 + (lane & 15);
        #pragma unroll
        for (int kk = 0; kk < 2; ++kk)
            aoff[kk][tm] = r * 64 + (((kk * 4 + (lane >> 4)) ^ (r & 7)) * 8);
    }
    #pragma unroll
    for (int tn = 0; tn < 4; ++tn) {
        int r = wn * 64 + tn * 16 + (lane & 15);
        #pragma unroll
        for (int kk = 0; kk < 2; ++kk)
            boff[kk][tn] = r * 64 + (((kk * 4 + (lane >> 4)) ^ (r & 7)) * 8);
    }

    f32x4 acc[4][4];
    #pragma unroll
    for (int a = 0; a < 4; ++a)
        #pragma unroll
        for (int c = 0; c < 4; ++c) acc[a][c] = (f32x4){0.f, 0.f, 0.f, 0.f};

    // main: K = 2048 over (xb, Wb), 32 iters of BK=64
    for (int it = 0; it < 32; ++it) {
        #pragma unroll
        for (int q = 0; q < 4; ++q) {
            __builtin_amdgcn_global_load_lds((GLOBAL_AS void*)pA[q],
                (LDS_AS void*)&lsA[ldso[q]], 16, 0, 0);
            __builtin_amdgcn_global_load_lds((GLOBAL_AS void*)pB[q],
                (LDS_AS void*)&lsB[ldso[q]], 16, 0, 0);
            pA[q] += 64; pB[q] += 64;
        }
        __syncthreads();
        #pragma unroll
        for (int kk = 0; kk < 2; ++kk) {
            bf16x8 af[4], bfr[4];
            #pragma unroll
            for (int tm = 0; tm < 4; ++tm) af[tm]  = *(const bf16x8*)&lsA[aoff[kk][tm]];
            #pragma unroll
            for (int tn = 0; tn < 4; ++tn) bfr[tn] = *(const bf16x8*)&lsB[boff[kk][tn]];
            #pragma unroll
            for (int tm = 0; tm < 4; ++tm)
                #pragma unroll
                for (int tn = 0; tn < 4; ++tn)
                    acc[tm][tn] = __builtin_amdgcn_mfma_f32_16x16x32_bf16(
                        af[tm], bfr[tn], acc[tm][tn], 0, 0, 0);
        }
        __syncthreads();
    }

    // correction: single BK=64 kstep over (tb, caug), stride KE=64
    {
        #pragma unroll
        for (int q = 0; q < 4; ++q) {
            const __bf16* qA = tb   + (size_t)(m0 + rowq[q]) * KE + segq[q] * 8;
            const __bf16* qB = caug + (size_t)(n0 + rowq[q]) * KE + segq[q] * 8;
            __builtin_amdgcn_global_load_lds((GLOBAL_AS void*)qA,
                (LDS_AS void*)&lsA[ldso[q]], 16, 0, 0);
            __builtin_amdgcn_global_load_lds((GLOBAL_AS void*)qB,
                (LDS_AS void*)&lsB[ldso[q]], 16, 0, 0);
        }
        __syncthreads();
        #pragma unroll
        for (int kk = 0; kk < 2; ++kk) {
            bf16x8 af[4], bfr[4];
            #pragma unroll
            for (int tm = 0; tm < 4; ++tm) af[tm]  = *(const bf16x8*)&lsA[aoff[kk][tm]];
            #pragma unroll
            for (int tn = 0; tn < 4; ++tn) bfr[tn] = *(const bf16x8*)&lsB[boff[kk][tn]];
            #pragma unroll
            for (int tm = 0; tm < 4; ++tm)
                #pragma unroll
                for (int tn = 0; tn < 4; ++tn)
                    acc[tm][tn] = __builtin_amdgcn_mfma_f32_16x16x32_bf16(
                        af[tm], bfr[tn], acc[tm][tn], 0, 0, 0);
        }
        __syncthreads();
    }

    #pragma unroll
    for (int tm = 0; tm < 4; ++tm)
        #pragma unroll
        for (int tn = 0; tn < 4; ++tn) {
            int col = n0 + wn * 64 + tn * 16 + (lane & 15);
            float bv = bias[col];
            #pragma unroll
            for (int v = 0; v < 4; ++v) {
                int row = m0 + wm * 64 + tm * 16 + (lane >> 4) * 4 + v;
                out[(size_t)row * DOUT + col] = acc[tm][tn][v] + bv;
            }
        }
}

// ---------------------------------------------------------------------------
// Workspace (bytes):
//   xb      @ 0         : 33,554,432   (8192x2048 bf16)
//   Wb      @ 33554432  :  8,388,608   (2048x2048 bf16, shared LoRA folded)
//   pt      @ 41943040  :  4,194,304   (4x8192x64 bf16)
//   tb      @ 46137344  :  1,048,576   (8192x64 bf16)
//   caug    @ 47185920  :    262,144   (2048x64 bf16)
//   Ab      @ 47448064  :    262,144   (64x2048 bf16)
//   partial @ 47710208  :  2,097,152   (4x64x2048 f32)
//   routing @ 49807360  :        256
// ---------------------------------------------------------------------------
extern "C" void kernel_launch(void* const* d_in, const int* in_sizes, int n_in,
                              void* d_out, int out_size, void* d_ws, size_t ws_size,
                              hipStream_t stream)
{
    const float* x        = (const float*)d_in[0];
    const float* base_W   = (const float*)d_in[1];
    const float* base_b   = (const float*)d_in[2];
    const float* shared_A = (const float*)d_in[3];
    const float* shared_B = (const float*)d_in[4];
    const float* expert_A = (const float*)d_in[5];
    const float* expert_B = (const float*)d_in[6];
    const float* task_emb = (const float*)d_in[7];
    const float* collab_w = (const float*)d_in[8];
    float* out = (float*)d_out;

    char* ws = (char*)d_ws;
    __bf16* xb      = (__bf16*)(ws + 0);
    __bf16* Wb      = (__bf16*)(ws + 33554432);
    __bf16* pt      = (__bf16*)(ws + 41943040);
    __bf16* tb      = (__bf16*)(ws + 46137344);
    __bf16* caug    = (__bf16*)(ws + 47185920);
    __bf16* Ab      = (__bf16*)(ws + 47448064);
    float*  partial = (float*) (ws + 47710208);
    float*  routing = (float*) (ws + 49807360);

    prep_all    <<<dim3(5760), 256, 0, stream>>>(x, base_W, expert_A, shared_A,
                                                 expert_B, shared_B, collab_w,
                                                 xb, partial, Wb, caug, Ab);
    gemm_t_rout <<<dim3(260), 256, 0, stream>>>(xb, Ab, partial, task_emb, pt, routing);
    reduce_route<<<dim3(512), 256, 0, stream>>>(pt, routing, tb);
    gemm_main   <<<dim3(64, 16), 256, 0, stream>>>(xb, Wb, tb, caug, base_b, out);
}